// Round 16
// baseline (233.028 us; speedup 1.0000x reference)
//
#include <hip/hip_runtime.h>

#define D 128
#define GNUM 512

typedef _Float16 f16;
typedef _Float16 f16x2 __attribute__((ext_vector_type(2)));
typedef _Float16 f16x8 __attribute__((ext_vector_type(8)));
typedef float f32x4 __attribute__((ext_vector_type(4)));

// ------------- hierarchical scan: per-block partial sums ------------------
__global__ __launch_bounds__(256) void partial_kernel(
    const int* __restrict__ deg, int* __restrict__ partials, int n) {
  __shared__ int sh[256];
  const int t = threadIdx.x;
  const int i = blockIdx.x * 512 + t * 2;
  int s = 0;
  if (i < n) s += deg[i];
  if (i + 1 < n) s += deg[i + 1];
  sh[t] = s;
  __syncthreads();
#pragma unroll
  for (int off = 128; off > 0; off >>= 1) {
    if (t < off) sh[t] += sh[t + off];
    __syncthreads();
  }
  if (t == 0) partials[blockIdx.x] = sh[0];
}

// ------------- hierarchical scan: scan the partials (1 block) -------------
__global__ __launch_bounds__(128) void scanp_kernel(
    int* __restrict__ partials, int nP, int* __restrict__ rowptr, int n,
    int nE) {
  __shared__ int sh[128];
  const int t = threadIdx.x;
  const int v = (t < nP) ? partials[t] : 0;
  sh[t] = v;
  __syncthreads();
#pragma unroll
  for (int off = 1; off < 128; off <<= 1) {
    int u = (t >= off) ? sh[t - off] : 0;
    __syncthreads();
    sh[t] += u;
    __syncthreads();
  }
  if (t < nP) partials[t] = sh[t] - v;
  if (t == 0) rowptr[n] = nE;
}

// ------------- hierarchical scan: emit rowptr/cursor ----------------------
__global__ __launch_bounds__(256) void emit_kernel(
    const int* __restrict__ deg, const int* __restrict__ partials,
    int* __restrict__ rowptr, int* __restrict__ cursor, int n) {
  __shared__ int sh[256];
  const int t = threadIdx.x;
  const int i = blockIdx.x * 512 + t * 2;
  const int d0 = (i < n) ? deg[i] : 0;
  const int d1 = (i + 1 < n) ? deg[i + 1] : 0;
  const int s = d0 + d1;
  sh[t] = s;
  __syncthreads();
#pragma unroll
  for (int off = 1; off < 256; off <<= 1) {
    int u = (t >= off) ? sh[t - off] : 0;
    __syncthreads();
    sh[t] += u;
    __syncthreads();
  }
  int base = partials[blockIdx.x] + sh[t] - s;
  if (i < n) {
    rowptr[i] = base;
    cursor[i] = base;
    base += d0;
  }
  if (i + 1 < n) {
    rowptr[i + 1] = base;
    cursor[i + 1] = base;
  }
}

// ---------------- CSR build: fill src lists ----------------
__global__ void fill_kernel(const int* __restrict__ ei, int* __restrict__ cursor,
                            int* __restrict__ csr, int nE) {
  int e = blockIdx.x * blockDim.x + threadIdx.x;
  if (e < nE) {
    int d = ei[nE + e];
    int pos = atomicAdd(&cursor[d], 1);
    csr[pos] = ei[e];
  }
}

// -- merged prep: xcvt (x->f16) | wprep (4x W_T) | gstart | deg histogram --
__global__ __launch_bounds__(256) void prep_kernel(
    const float* __restrict__ x, f16* __restrict__ x16, int n4,
    const float* __restrict__ W0, const float* __restrict__ W1,
    const float* __restrict__ W2, const float* __restrict__ W3,
    f16* __restrict__ wt, const int* __restrict__ batch,
    int* __restrict__ gstart, const int* __restrict__ ei,
    int* __restrict__ deg, int nE, int n, int nxblk) {
  const int b = blockIdx.x;
  if (b < nxblk) {
    int i = b * 256 + threadIdx.x;
    if (i < n4) {
      float4 v = ((const float4*)x)[i];
      union { f16 h[4]; uint2 u; } p;
      p.h[0] = (f16)v.x; p.h[1] = (f16)v.y;
      p.h[2] = (f16)v.z; p.h[3] = (f16)v.w;
      ((uint2*)x16)[i] = p.u;
    }
  } else if (b < nxblk + 256) {
    int idx = (b - nxblk) * 256 + threadIdx.x;  // 65536 total
    int wsel = idx >> 14;
    int rem = idx & 16383;
    int col = rem >> 7, k = rem & 127;
    const float* W = (wsel == 0) ? W0 : (wsel == 1) ? W1
                                      : (wsel == 2) ? W2 : W3;
    wt[idx] = (f16)W[k * D + col];
  } else if (b < nxblk + 259) {
    int g = (b - nxblk - 256) * 256 + threadIdx.x;
    if (g > GNUM) return;
    if (g == GNUM) { gstart[g] = n; return; }
    int lo = 0, hi = n;
    while (lo < hi) {
      int mid = (lo + hi) >> 1;
      if (batch[mid] < g) lo = mid + 1; else hi = mid;
    }
    gstart[g] = lo;
  } else {
    int e = (b - nxblk - 259) * 256 + threadIdx.x;
    if (e < nE) atomicAdd(&deg[ei[nE + e]], 1);
  }
}

// ------- fused gather + GEMM1 + stats: hpre = gather(feat) @ W + b --------
// Block = 256 thr (4 waves) = 32 rows. Phase 1: wave w gathers rows
// [rb+w*8, rb+w*8+8) wave-per-row (lane owns 2 cols, 8x unroll) into LDS
// (padded stride 136 f16). Phase 2: wave w computes 32 rows x 32 cols
// (col base w*32) via MFMA from LDS; epilogue stores f16 C and atomically
// accumulates col sum/sumsq into stats arena pstat2[blk&31][256].
__global__ __launch_bounds__(256) void gemmfused_kernel(
    const f16* __restrict__ feat, const int* __restrict__ rowptr,
    const int* __restrict__ csr, const f16* __restrict__ WT,
    const float* __restrict__ bias, f16* __restrict__ C,
    float* __restrict__ pstat2, int n) {
  __shared__ f16 alds[32][136];
  const int t = threadIdx.x;
  const int w = t >> 6;
  const int l = t & 63;
  const int rb = blockIdx.x * 32;

  // ---------------- phase 1: gather ----------------
  {
    const int c = l * 2;
#pragma unroll 1
    for (int rr = w * 8; rr < w * 8 + 8; rr++) {
      const int row = rb + rr;
      float a0 = 0.f, a1 = 0.f;
      if (row < n) {
        f16x2 v = *(const f16x2*)(feat + (size_t)row * D + c);
        a0 = (float)v[0]; a1 = (float)v[1];
        const int beg = rowptr[row], end = rowptr[row + 1];
        int i = beg;
        for (; i + 7 < end; i += 8) {   // 8 independent loads in flight
          int s0 = csr[i],     s1 = csr[i + 1], s2 = csr[i + 2], s3 = csr[i + 3];
          int s4 = csr[i + 4], s5 = csr[i + 5], s6 = csr[i + 6], s7 = csr[i + 7];
          f16x2 v0 = *(const f16x2*)(feat + (size_t)s0 * D + c);
          f16x2 v1 = *(const f16x2*)(feat + (size_t)s1 * D + c);
          f16x2 v2 = *(const f16x2*)(feat + (size_t)s2 * D + c);
          f16x2 v3 = *(const f16x2*)(feat + (size_t)s3 * D + c);
          f16x2 v4 = *(const f16x2*)(feat + (size_t)s4 * D + c);
          f16x2 v5 = *(const f16x2*)(feat + (size_t)s5 * D + c);
          f16x2 v6 = *(const f16x2*)(feat + (size_t)s6 * D + c);
          f16x2 v7 = *(const f16x2*)(feat + (size_t)s7 * D + c);
          a0 += ((float)v0[0] + (float)v1[0]) + ((float)v2[0] + (float)v3[0]) +
                ((float)v4[0] + (float)v5[0]) + ((float)v6[0] + (float)v7[0]);
          a1 += ((float)v0[1] + (float)v1[1]) + ((float)v2[1] + (float)v3[1]) +
                ((float)v4[1] + (float)v5[1]) + ((float)v6[1] + (float)v7[1]);
        }
        for (; i + 3 < end; i += 4) {
          int s0 = csr[i], s1 = csr[i + 1], s2 = csr[i + 2], s3 = csr[i + 3];
          f16x2 v0 = *(const f16x2*)(feat + (size_t)s0 * D + c);
          f16x2 v1 = *(const f16x2*)(feat + (size_t)s1 * D + c);
          f16x2 v2 = *(const f16x2*)(feat + (size_t)s2 * D + c);
          f16x2 v3 = *(const f16x2*)(feat + (size_t)s3 * D + c);
          a0 += (float)v0[0] + (float)v1[0] + (float)v2[0] + (float)v3[0];
          a1 += (float)v0[1] + (float)v1[1] + (float)v2[1] + (float)v3[1];
        }
        for (; i < end; i++) {
          f16x2 v = *(const f16x2*)(feat + (size_t)csr[i] * D + c);
          a0 += (float)v[0];
          a1 += (float)v[1];
        }
      }
      f16x2 o;
      o[0] = (f16)a0;
      o[1] = (f16)a1;
      *(f16x2*)(&alds[rr][c]) = o;
    }
  }
  __syncthreads();

  // ---------------- phase 2: 32x32 MFMA quadrant per wave ----------------
  const int lr = l & 15;
  const int lq = l >> 4;
  const int lk = lq * 8;
  const int cb = w * 32;

  f32x4 acc[2][2];
#pragma unroll
  for (int m = 0; m < 2; m++)
#pragma unroll
    for (int nt = 0; nt < 2; nt++) acc[m][nt] = (f32x4)0.f;

#pragma unroll
  for (int s = 0; s < 4; s++) {
    const int k = s * 32 + lk;
    f16x8 af[2];
#pragma unroll
    for (int m = 0; m < 2; m++)
      af[m] = *(const f16x8*)(&alds[m * 16 + lr][k]);
    f16x8 bf[2];
#pragma unroll
    for (int nt = 0; nt < 2; nt++)
      bf[nt] = *(const f16x8*)(WT + (size_t)(cb + nt * 16 + lr) * D + k);
#pragma unroll
    for (int m = 0; m < 2; m++)
#pragma unroll
      for (int nt = 0; nt < 2; nt++)
        acc[m][nt] = __builtin_amdgcn_mfma_f32_16x16x32_f16(af[m], bf[nt],
                                                            acc[m][nt], 0, 0, 0);
  }

  // ---------------- epilogue: bias, store f16, col stats ----------------
  float ts[2], tq[2];
#pragma unroll
  for (int nt = 0; nt < 2; nt++) { ts[nt] = 0.f; tq[nt] = 0.f; }
#pragma unroll
  for (int m = 0; m < 2; m++)
#pragma unroll
    for (int r = 0; r < 4; r++) {
      int row = rb + m * 16 + lq * 4 + r;
      if (row < n) {
#pragma unroll
        for (int nt = 0; nt < 2; nt++) {
          float v = acc[m][nt][r] + bias[cb + nt * 16 + lr];
          C[(size_t)row * D + cb + nt * 16 + lr] = (f16)v;
          ts[nt] += v;
          tq[nt] = fmaf(v, v, tq[nt]);
        }
      }
    }
#pragma unroll
  for (int nt = 0; nt < 2; nt++) {
    ts[nt] += __shfl_xor(ts[nt], 16); ts[nt] += __shfl_xor(ts[nt], 32);
    tq[nt] += __shfl_xor(tq[nt], 16); tq[nt] += __shfl_xor(tq[nt], 32);
  }
  if (l < 16) {
    float* ps = pstat2 + (size_t)(blockIdx.x & 31) * 256;
#pragma unroll
    for (int nt = 0; nt < 2; nt++) {
      atomicAdd(ps + cb + nt * 16 + l, ts[nt]);
      atomicAdd(ps + 128 + cb + nt * 16 + l, tq[nt]);
    }
  }
}

// ------ BN-GEMM: C = relu( relu(A*ss+sh) @ W + b ), 1 wave = 16 rows ------
// 16-row tile => 3125 waves (~12/CU) for latency hiding (isolated re-test
// of round-7's tile change, previously confounded with agg regression).
__global__ __launch_bounds__(64) void gemmbn_kernel(
    const f16* __restrict__ A, const float* __restrict__ ss,
    const f16* __restrict__ WT, const float* __restrict__ bias,
    f16* __restrict__ C, int n) {
  const int l = threadIdx.x;
  const int rw0 = blockIdx.x * 16;
  const int lr = l & 15;
  const int lq = l >> 4;
  const int lk = lq * 8;

  f32x4 acc[8];
#pragma unroll
  for (int nt = 0; nt < 8; nt++) acc[nt] = (f32x4)0.f;

#pragma unroll
  for (int s = 0; s < 4; s++) {
    const int k = s * 32 + lk;
    float4 c0 = *(const float4*)(ss + k);
    float4 c1 = *(const float4*)(ss + k + 4);
    float4 h0 = *(const float4*)(ss + 128 + k);
    float4 h1 = *(const float4*)(ss + 128 + k + 4);
    const int row = rw0 + lr;
    f16x8 v = (f16x8)(f16)0.f;
    if (row < n) v = *(const f16x8*)(A + (size_t)row * D + k);
    f16x8 af;
    af[0] = (f16)fmaxf(0.f, fmaf((float)v[0], c0.x, h0.x));
    af[1] = (f16)fmaxf(0.f, fmaf((float)v[1], c0.y, h0.y));
    af[2] = (f16)fmaxf(0.f, fmaf((float)v[2], c0.z, h0.z));
    af[3] = (f16)fmaxf(0.f, fmaf((float)v[3], c0.w, h0.w));
    af[4] = (f16)fmaxf(0.f, fmaf((float)v[4], c1.x, h1.x));
    af[5] = (f16)fmaxf(0.f, fmaf((float)v[5], c1.y, h1.y));
    af[6] = (f16)fmaxf(0.f, fmaf((float)v[6], c1.z, h1.z));
    af[7] = (f16)fmaxf(0.f, fmaf((float)v[7], c1.w, h1.w));
    f16x8 bf[8];
#pragma unroll
    for (int nt = 0; nt < 8; nt++)
      bf[nt] = *(const f16x8*)(WT + (size_t)(nt * 16 + lr) * D + k);
#pragma unroll
    for (int nt = 0; nt < 8; nt++)
      acc[nt] = __builtin_amdgcn_mfma_f32_16x16x32_f16(af, bf[nt], acc[nt],
                                                       0, 0, 0);
  }

#pragma unroll
  for (int r = 0; r < 4; r++) {
    int row = rw0 + lq * 4 + r;
    if (row < n) {
#pragma unroll
      for (int nt = 0; nt < 8; nt++) {
        float v = fmaxf(0.f, acc[nt][r] + bias[nt * 16 + lr]);
        C[(size_t)row * D + nt * 16 + lr] = (f16)v;
      }
    }
  }
}

// ------------- BN stats: reduce pstat2 arena -> scale/shift ---------------
__global__ void bnstats_kernel(const float* __restrict__ pstat2,
                               const float* __restrict__ g,
                               const float* __restrict__ be,
                               float* __restrict__ ss, int n) {
  int c = threadIdx.x;  // 128
  float s = 0.f, sq = 0.f;
#pragma unroll
  for (int i = 0; i < 32; i++) {
    s += pstat2[i * 256 + c];
    sq += pstat2[i * 256 + 128 + c];
  }
  float inv_n = 1.0f / (float)n;
  float mean = s * inv_n;
  float var = sq * inv_n - mean * mean;
  float scale = g[c] * rsqrtf(var + 1e-5f);
  ss[c] = scale;
  ss[128 + c] = be[c] - mean * scale;
}

// ------- fused readout, 2 graphs/block (256 blocks) -----------------------
__global__ __launch_bounds__(512) void poolout_kernel(
    const f16* __restrict__ h1, const f16* __restrict__ h2,
    const int* __restrict__ gstart, const float* __restrict__ W1,
    const float* __restrict__ b1, const float* __restrict__ W2,
    const float* __restrict__ b2, float* __restrict__ out) {
  __shared__ float prow[2][512];
  __shared__ float shred[8][2];
  const int t = threadIdx.x;
  const int g0 = blockIdx.x * 2;
  {
    const int sub = t >> 8;            // graph within block (0,1)
    const int src = (t >> 7) & 1;      // 0: h1, 1: h2
    const int c = t & 127;             // column
    const f16* hp = src ? h2 : h1;
    const int r0 = gstart[g0 + sub], r1 = gstart[g0 + sub + 1];
    float s = 0.f, m = 0.f;
    int r = r0;
    for (; r + 1 < r1; r += 2) {
      float a = (float)hp[(size_t)r * D + c];
      float b = (float)hp[(size_t)(r + 1) * D + c];
      s += a + b;
      m = fmaxf(m, fmaxf(a, b));
    }
    if (r < r1) {
      float a = (float)hp[(size_t)r * D + c];
      s += a;
      m = fmaxf(m, a);
    }
    prow[sub][src * 128 + c] = s;        // k-layout: a1,a2,m1,m2
    prow[sub][256 + src * 128 + c] = m;
  }
  __syncthreads();
  float a00 = 0.f, a01 = 0.f, a10 = 0.f, a11 = 0.f;
  for (int k = 0; k < 512; k += 2) {
    float w0 = W1[(size_t)k * 512 + t];
    float w1 = W1[(size_t)(k + 1) * 512 + t];
    a00 = fmaf(prow[0][k], w0, a00);
    a01 = fmaf(prow[0][k + 1], w1, a01);
    a10 = fmaf(prow[1][k], w0, a10);
    a11 = fmaf(prow[1][k + 1], w1, a11);
  }
  const float bj = b1[t];
  const float w2 = W2[t];
  float acc0 = fmaxf(0.f, a00 + a01 + bj) * w2;
  float acc1 = fmaxf(0.f, a10 + a11 + bj) * w2;
  const int w = t >> 6, l = t & 63;
#pragma unroll
  for (int off = 32; off > 0; off >>= 1) {
    acc0 += __shfl_down(acc0, off);
    acc1 += __shfl_down(acc1, off);
  }
  if (l == 0) {
    shred[w][0] = acc0;
    shred[w][1] = acc1;
  }
  __syncthreads();
  if (t < 2) {
    float s = 0.f;
#pragma unroll
    for (int i = 0; i < 8; i++) s += shred[i][t];
    float h = s + b2[0];
    out[g0 + t] = 1.0f / (1.0f + expf(-h));
    out[GNUM + g0 + t] = h;
  }
}

extern "C" void kernel_launch(void* const* d_in, const int* in_sizes, int n_in,
                              void* d_out, int out_size, void* d_ws,
                              size_t ws_size, hipStream_t stream) {
  const float* x = (const float*)d_in[0];
  const int* ei = (const int*)d_in[1];
  const int* batch = (const int*)d_in[2];
  const float* c1_W1 = (const float*)d_in[3];
  const float* c1_b1 = (const float*)d_in[4];
  const float* c1_g  = (const float*)d_in[5];
  const float* c1_be = (const float*)d_in[6];
  const float* c1_W2 = (const float*)d_in[7];
  const float* c1_b2 = (const float*)d_in[8];
  const float* c2_W1 = (const float*)d_in[9];
  const float* c2_b1 = (const float*)d_in[10];
  const float* c2_g  = (const float*)d_in[11];
  const float* c2_be = (const float*)d_in[12];
  const float* c2_W2 = (const float*)d_in[13];
  const float* c2_b2 = (const float*)d_in[14];
  const float* lin1_W = (const float*)d_in[15];
  const float* lin1_b = (const float*)d_in[16];
  const float* lin2_W = (const float*)d_in[17];
  const float* lin2_b = (const float*)d_in[18];

  const int n = in_sizes[0] / D;        // 50000
  const int nE = in_sizes[1] / 2;       // 600000

  char* p = (char*)d_ws;
  auto take = [&](size_t bytes) {
    char* r = p;
    p += (bytes + 255) & ~(size_t)255;
    return r;
  };
  f16*   hpre   = (f16*)take((size_t)n * D * 2);   // fused GEMM1 out (f16)
  f16*   h2buf  = (f16*)take((size_t)n * D * 2);   // h2
  f16*   h1     = (f16*)take((size_t)n * D * 2);   // x16, then h1
  f16*   wt     = (f16*)take(4 * 16384 * 2);       // 4x W_T f16
  // deg + both stat arenas: contiguous, zeroed by one memset
  int*   deg     = (int*)take((size_t)n * 4);
  float* pstat2a = (float*)take(32 * 256 * 4);
  float* pstat2b = (float*)take(32 * 256 * 4);
  char*  zend    = p;
  float* ssbuf  = (float*)take(256 * 4);
  int*   gstart = (int*)take((GNUM + 1) * 4);
  int* rowptr   = (int*)take((size_t)(n + 1) * 4);
  int* cursor   = (int*)take((size_t)(n + 1) * 4);
  int* partials = (int*)take(128 * 4);
  int* csr      = (int*)take((size_t)nE * 4);
  const int nB = (n + 31) / 32;                    // 1563 gemmfused blocks
  const int nBn = (n + 15) / 16;                   // 3125 gemmbn blocks

  const int edge_grid = (nE + 255) / 256;
  const int nP = (n + 511) / 512;
  const int n4 = n * D / 4;
  const int nxblk = (n4 + 255) / 256;              // xcvt blocks
  const int prep_grid = nxblk + 259 + edge_grid;   // +wprep +gstart +deg

  // ---------------- prep (deg fused into prep_kernel) ----------------
  hipMemsetAsync(deg, 0, (size_t)(zend - (char*)deg), stream);
  prep_kernel<<<prep_grid, 256, 0, stream>>>(x, h1, n4, c1_W1, c1_W2, c2_W1,
                                             c2_W2, wt, batch, gstart, ei,
                                             deg, nE, n, nxblk);
  partial_kernel<<<nP, 256, 0, stream>>>(deg, partials, n);
  scanp_kernel<<<1, 128, 0, stream>>>(partials, nP, rowptr, n, nE);
  emit_kernel<<<nP, 256, 0, stream>>>(deg, partials, rowptr, cursor, n);
  fill_kernel<<<edge_grid, 256, 0, stream>>>(ei, cursor, csr, nE);

  // ---------------- layer 1 (gather fused into GEMM1) ----------------
  gemmfused_kernel<<<nB, 256, 0, stream>>>(h1, rowptr, csr, wt, c1_b1, hpre,
                                           pstat2a, n);
  bnstats_kernel<<<1, 128, 0, stream>>>(pstat2a, c1_g, c1_be, ssbuf, n);
  gemmbn_kernel<<<nBn, 64, 0, stream>>>(hpre, ssbuf, wt + 16384, c1_b2, h1, n);

  // ---------------- layer 2 (gather fused into GEMM1) ----------------
  gemmfused_kernel<<<nB, 256, 0, stream>>>(h1, rowptr, csr, wt + 32768, c2_b1,
                                           hpre, pstat2b, n);
  bnstats_kernel<<<1, 128, 0, stream>>>(pstat2b, c2_g, c2_be, ssbuf, n);
  gemmbn_kernel<<<nBn, 64, 0, stream>>>(hpre, ssbuf, wt + 49152, c2_b2,
                                        h2buf, n);

  // ---------------- fused pooling + readout (2 graphs/block) --------------
  poolout_kernel<<<GNUM / 2, 512, 0, stream>>>(h1, h2buf, gstart, lin1_W,
                                               lin1_b, lin2_W, lin2_b,
                                               (float*)d_out);
}

// Round 17
// 228.470 us; speedup vs baseline: 1.0199x; 1.0199x over previous
//
#include <hip/hip_runtime.h>

#define D 128
#define GNUM 512

typedef _Float16 f16;
typedef _Float16 f16x2 __attribute__((ext_vector_type(2)));
typedef _Float16 f16x8 __attribute__((ext_vector_type(8)));
typedef float f32x4 __attribute__((ext_vector_type(4)));

// ------------- hierarchical scan: per-block partial sums ------------------
__global__ __launch_bounds__(256) void partial_kernel(
    const int* __restrict__ deg, int* __restrict__ partials, int n) {
  __shared__ int sh[256];
  const int t = threadIdx.x;
  const int i = blockIdx.x * 512 + t * 2;
  int s = 0;
  if (i < n) s += deg[i];
  if (i + 1 < n) s += deg[i + 1];
  sh[t] = s;
  __syncthreads();
#pragma unroll
  for (int off = 128; off > 0; off >>= 1) {
    if (t < off) sh[t] += sh[t + off];
    __syncthreads();
  }
  if (t == 0) partials[blockIdx.x] = sh[0];
}

// ------------- hierarchical scan: scan the partials (1 block) -------------
__global__ __launch_bounds__(128) void scanp_kernel(
    int* __restrict__ partials, int nP, int* __restrict__ rowptr, int n,
    int nE) {
  __shared__ int sh[128];
  const int t = threadIdx.x;
  const int v = (t < nP) ? partials[t] : 0;
  sh[t] = v;
  __syncthreads();
#pragma unroll
  for (int off = 1; off < 128; off <<= 1) {
    int u = (t >= off) ? sh[t - off] : 0;
    __syncthreads();
    sh[t] += u;
    __syncthreads();
  }
  if (t < nP) partials[t] = sh[t] - v;
  if (t == 0) rowptr[n] = nE;
}

// ------------- hierarchical scan: emit rowptr/cursor ----------------------
__global__ __launch_bounds__(256) void emit_kernel(
    const int* __restrict__ deg, const int* __restrict__ partials,
    int* __restrict__ rowptr, int* __restrict__ cursor, int n) {
  __shared__ int sh[256];
  const int t = threadIdx.x;
  const int i = blockIdx.x * 512 + t * 2;
  const int d0 = (i < n) ? deg[i] : 0;
  const int d1 = (i + 1 < n) ? deg[i + 1] : 0;
  const int s = d0 + d1;
  sh[t] = s;
  __syncthreads();
#pragma unroll
  for (int off = 1; off < 256; off <<= 1) {
    int u = (t >= off) ? sh[t - off] : 0;
    __syncthreads();
    sh[t] += u;
    __syncthreads();
  }
  int base = partials[blockIdx.x] + sh[t] - s;
  if (i < n) {
    rowptr[i] = base;
    cursor[i] = base;
    base += d0;
  }
  if (i + 1 < n) {
    rowptr[i + 1] = base;
    cursor[i + 1] = base;
  }
}

// ---------------- CSR build: fill src lists ----------------
__global__ void fill_kernel(const int* __restrict__ ei, int* __restrict__ cursor,
                            int* __restrict__ csr, int nE) {
  int e = blockIdx.x * blockDim.x + threadIdx.x;
  if (e < nE) {
    int d = ei[nE + e];
    int pos = atomicAdd(&cursor[d], 1);
    csr[pos] = ei[e];
  }
}

// -- merged prep: xcvt (x->f16) | wprep (4x W_T) | gstart | deg histogram --
__global__ __launch_bounds__(256) void prep_kernel(
    const float* __restrict__ x, f16* __restrict__ x16, int n4,
    const float* __restrict__ W0, const float* __restrict__ W1,
    const float* __restrict__ W2, const float* __restrict__ W3,
    f16* __restrict__ wt, const int* __restrict__ batch,
    int* __restrict__ gstart, const int* __restrict__ ei,
    int* __restrict__ deg, int nE, int n, int nxblk) {
  const int b = blockIdx.x;
  if (b < nxblk) {
    int i = b * 256 + threadIdx.x;
    if (i < n4) {
      float4 v = ((const float4*)x)[i];
      union { f16 h[4]; uint2 u; } p;
      p.h[0] = (f16)v.x; p.h[1] = (f16)v.y;
      p.h[2] = (f16)v.z; p.h[3] = (f16)v.w;
      ((uint2*)x16)[i] = p.u;
    }
  } else if (b < nxblk + 256) {
    int idx = (b - nxblk) * 256 + threadIdx.x;  // 65536 total
    int wsel = idx >> 14;
    int rem = idx & 16383;
    int col = rem >> 7, k = rem & 127;
    const float* W = (wsel == 0) ? W0 : (wsel == 1) ? W1
                                      : (wsel == 2) ? W2 : W3;
    wt[idx] = (f16)W[k * D + col];
  } else if (b < nxblk + 259) {
    int g = (b - nxblk - 256) * 256 + threadIdx.x;
    if (g > GNUM) return;
    if (g == GNUM) { gstart[g] = n; return; }
    int lo = 0, hi = n;
    while (lo < hi) {
      int mid = (lo + hi) >> 1;
      if (batch[mid] < g) lo = mid + 1; else hi = mid;
    }
    gstart[g] = lo;
  } else {
    int e = (b - nxblk - 259) * 256 + threadIdx.x;
    if (e < nE) atomicAdd(&deg[ei[nE + e]], 1);
  }
}

// ------- fused gather + GEMM1 + stats: hpre = gather(feat) @ W + b --------
// Block = 256 thr (4 waves) = 32 rows. Phase 1: wave w gathers rows
// [rb+w*8, rb+w*8+8) wave-per-row (lane owns 2 cols, 8x unroll) into LDS
// (padded stride 136 f16). Phase 2: wave w computes 32 rows x 32 cols
// (col base w*32) via MFMA from LDS; epilogue stores f16 C and atomically
// accumulates col sum/sumsq into stats arena pstat2[blk&31][256].
__global__ __launch_bounds__(256) void gemmfused_kernel(
    const f16* __restrict__ feat, const int* __restrict__ rowptr,
    const int* __restrict__ csr, const f16* __restrict__ WT,
    const float* __restrict__ bias, f16* __restrict__ C,
    float* __restrict__ pstat2, int n) {
  __shared__ f16 alds[32][136];
  const int t = threadIdx.x;
  const int w = t >> 6;
  const int l = t & 63;
  const int rb = blockIdx.x * 32;

  // ---------------- phase 1: gather ----------------
  {
    const int c = l * 2;
#pragma unroll 1
    for (int rr = w * 8; rr < w * 8 + 8; rr++) {
      const int row = rb + rr;
      float a0 = 0.f, a1 = 0.f;
      if (row < n) {
        f16x2 v = *(const f16x2*)(feat + (size_t)row * D + c);
        a0 = (float)v[0]; a1 = (float)v[1];
        const int beg = rowptr[row], end = rowptr[row + 1];
        int i = beg;
        for (; i + 7 < end; i += 8) {   // 8 independent loads in flight
          int s0 = csr[i],     s1 = csr[i + 1], s2 = csr[i + 2], s3 = csr[i + 3];
          int s4 = csr[i + 4], s5 = csr[i + 5], s6 = csr[i + 6], s7 = csr[i + 7];
          f16x2 v0 = *(const f16x2*)(feat + (size_t)s0 * D + c);
          f16x2 v1 = *(const f16x2*)(feat + (size_t)s1 * D + c);
          f16x2 v2 = *(const f16x2*)(feat + (size_t)s2 * D + c);
          f16x2 v3 = *(const f16x2*)(feat + (size_t)s3 * D + c);
          f16x2 v4 = *(const f16x2*)(feat + (size_t)s4 * D + c);
          f16x2 v5 = *(const f16x2*)(feat + (size_t)s5 * D + c);
          f16x2 v6 = *(const f16x2*)(feat + (size_t)s6 * D + c);
          f16x2 v7 = *(const f16x2*)(feat + (size_t)s7 * D + c);
          a0 += ((float)v0[0] + (float)v1[0]) + ((float)v2[0] + (float)v3[0]) +
                ((float)v4[0] + (float)v5[0]) + ((float)v6[0] + (float)v7[0]);
          a1 += ((float)v0[1] + (float)v1[1]) + ((float)v2[1] + (float)v3[1]) +
                ((float)v4[1] + (float)v5[1]) + ((float)v6[1] + (float)v7[1]);
        }
        for (; i + 3 < end; i += 4) {
          int s0 = csr[i], s1 = csr[i + 1], s2 = csr[i + 2], s3 = csr[i + 3];
          f16x2 v0 = *(const f16x2*)(feat + (size_t)s0 * D + c);
          f16x2 v1 = *(const f16x2*)(feat + (size_t)s1 * D + c);
          f16x2 v2 = *(const f16x2*)(feat + (size_t)s2 * D + c);
          f16x2 v3 = *(const f16x2*)(feat + (size_t)s3 * D + c);
          a0 += (float)v0[0] + (float)v1[0] + (float)v2[0] + (float)v3[0];
          a1 += (float)v0[1] + (float)v1[1] + (float)v2[1] + (float)v3[1];
        }
        for (; i < end; i++) {
          f16x2 v = *(const f16x2*)(feat + (size_t)csr[i] * D + c);
          a0 += (float)v[0];
          a1 += (float)v[1];
        }
      }
      f16x2 o;
      o[0] = (f16)a0;
      o[1] = (f16)a1;
      *(f16x2*)(&alds[rr][c]) = o;
    }
  }
  __syncthreads();

  // ---------------- phase 2: 32x32 MFMA quadrant per wave ----------------
  const int lr = l & 15;
  const int lq = l >> 4;
  const int lk = lq * 8;
  const int cb = w * 32;

  f32x4 acc[2][2];
#pragma unroll
  for (int m = 0; m < 2; m++)
#pragma unroll
    for (int nt = 0; nt < 2; nt++) acc[m][nt] = (f32x4)0.f;

#pragma unroll
  for (int s = 0; s < 4; s++) {
    const int k = s * 32 + lk;
    f16x8 af[2];
#pragma unroll
    for (int m = 0; m < 2; m++)
      af[m] = *(const f16x8*)(&alds[m * 16 + lr][k]);
    f16x8 bf[2];
#pragma unroll
    for (int nt = 0; nt < 2; nt++)
      bf[nt] = *(const f16x8*)(WT + (size_t)(cb + nt * 16 + lr) * D + k);
#pragma unroll
    for (int m = 0; m < 2; m++)
#pragma unroll
      for (int nt = 0; nt < 2; nt++)
        acc[m][nt] = __builtin_amdgcn_mfma_f32_16x16x32_f16(af[m], bf[nt],
                                                            acc[m][nt], 0, 0, 0);
  }

  // ---------------- epilogue: bias, store f16, col stats ----------------
  float ts[2], tq[2];
#pragma unroll
  for (int nt = 0; nt < 2; nt++) { ts[nt] = 0.f; tq[nt] = 0.f; }
#pragma unroll
  for (int m = 0; m < 2; m++)
#pragma unroll
    for (int r = 0; r < 4; r++) {
      int row = rb + m * 16 + lq * 4 + r;
      if (row < n) {
#pragma unroll
        for (int nt = 0; nt < 2; nt++) {
          float v = acc[m][nt][r] + bias[cb + nt * 16 + lr];
          C[(size_t)row * D + cb + nt * 16 + lr] = (f16)v;
          ts[nt] += v;
          tq[nt] = fmaf(v, v, tq[nt]);
        }
      }
    }
#pragma unroll
  for (int nt = 0; nt < 2; nt++) {
    ts[nt] += __shfl_xor(ts[nt], 16); ts[nt] += __shfl_xor(ts[nt], 32);
    tq[nt] += __shfl_xor(tq[nt], 16); tq[nt] += __shfl_xor(tq[nt], 32);
  }
  if (l < 16) {
    float* ps = pstat2 + (size_t)(blockIdx.x & 31) * 256;
#pragma unroll
    for (int nt = 0; nt < 2; nt++) {
      atomicAdd(ps + cb + nt * 16 + l, ts[nt]);
      atomicAdd(ps + 128 + cb + nt * 16 + l, tq[nt]);
    }
  }
}

// ------ BN-GEMM: C = relu( relu(A*ss+sh) @ W + b ), 1 wave = 32 rows ------
__global__ __launch_bounds__(64) void gemmbn_kernel(
    const f16* __restrict__ A, const float* __restrict__ ss,
    const f16* __restrict__ WT, const float* __restrict__ bias,
    f16* __restrict__ C, int n) {
  const int l = threadIdx.x;
  const int rw0 = blockIdx.x * 32;
  const int lr = l & 15;
  const int lq = l >> 4;
  const int lk = lq * 8;

  f32x4 acc[2][8];
#pragma unroll
  for (int m = 0; m < 2; m++)
#pragma unroll
    for (int nt = 0; nt < 8; nt++) acc[m][nt] = (f32x4)0.f;

#pragma unroll
  for (int s = 0; s < 4; s++) {
    const int k = s * 32 + lk;
    float4 c0 = *(const float4*)(ss + k);
    float4 c1 = *(const float4*)(ss + k + 4);
    float4 h0 = *(const float4*)(ss + 128 + k);
    float4 h1 = *(const float4*)(ss + 128 + k + 4);
    f16x8 af[2];
#pragma unroll
    for (int m = 0; m < 2; m++) {
      int row = rw0 + m * 16 + lr;
      f16x8 v = (f16x8)(f16)0.f;
      if (row < n) v = *(const f16x8*)(A + (size_t)row * D + k);
      f16x8 r;
      r[0] = (f16)fmaxf(0.f, fmaf((float)v[0], c0.x, h0.x));
      r[1] = (f16)fmaxf(0.f, fmaf((float)v[1], c0.y, h0.y));
      r[2] = (f16)fmaxf(0.f, fmaf((float)v[2], c0.z, h0.z));
      r[3] = (f16)fmaxf(0.f, fmaf((float)v[3], c0.w, h0.w));
      r[4] = (f16)fmaxf(0.f, fmaf((float)v[4], c1.x, h1.x));
      r[5] = (f16)fmaxf(0.f, fmaf((float)v[5], c1.y, h1.y));
      r[6] = (f16)fmaxf(0.f, fmaf((float)v[6], c1.z, h1.z));
      r[7] = (f16)fmaxf(0.f, fmaf((float)v[7], c1.w, h1.w));
      af[m] = r;
    }
    f16x8 bf[8];
#pragma unroll
    for (int nt = 0; nt < 8; nt++)
      bf[nt] = *(const f16x8*)(WT + (size_t)(nt * 16 + lr) * D + k);
#pragma unroll
    for (int m = 0; m < 2; m++)
#pragma unroll
      for (int nt = 0; nt < 8; nt++)
        acc[m][nt] = __builtin_amdgcn_mfma_f32_16x16x32_f16(af[m], bf[nt],
                                                            acc[m][nt], 0, 0, 0);
  }

#pragma unroll
  for (int m = 0; m < 2; m++)
#pragma unroll
    for (int r = 0; r < 4; r++) {
      int row = rw0 + m * 16 + lq * 4 + r;
      if (row < n) {
#pragma unroll
        for (int nt = 0; nt < 8; nt++) {
          float v = fmaxf(0.f, acc[m][nt][r] + bias[nt * 16 + lr]);
          C[(size_t)row * D + nt * 16 + lr] = (f16)v;
        }
      }
    }
}

// ------------- BN stats: reduce pstat2 arena -> scale/shift ---------------
__global__ void bnstats_kernel(const float* __restrict__ pstat2,
                               const float* __restrict__ g,
                               const float* __restrict__ be,
                               float* __restrict__ ss, int n) {
  int c = threadIdx.x;  // 128
  float s = 0.f, sq = 0.f;
#pragma unroll
  for (int i = 0; i < 32; i++) {
    s += pstat2[i * 256 + c];
    sq += pstat2[i * 256 + 128 + c];
  }
  float inv_n = 1.0f / (float)n;
  float mean = s * inv_n;
  float var = sq * inv_n - mean * mean;
  float scale = g[c] * rsqrtf(var + 1e-5f);
  ss[c] = scale;
  ss[128 + c] = be[c] - mean * scale;
}

// ------- fused readout, 2 graphs/block (256 blocks) -----------------------
__global__ __launch_bounds__(512) void poolout_kernel(
    const f16* __restrict__ h1, const f16* __restrict__ h2,
    const int* __restrict__ gstart, const float* __restrict__ W1,
    const float* __restrict__ b1, const float* __restrict__ W2,
    const float* __restrict__ b2, float* __restrict__ out) {
  __shared__ float prow[2][512];
  __shared__ float shred[8][2];
  const int t = threadIdx.x;
  const int g0 = blockIdx.x * 2;
  {
    const int sub = t >> 8;            // graph within block (0,1)
    const int src = (t >> 7) & 1;      // 0: h1, 1: h2
    const int c = t & 127;             // column
    const f16* hp = src ? h2 : h1;
    const int r0 = gstart[g0 + sub], r1 = gstart[g0 + sub + 1];
    float s = 0.f, m = 0.f;
    int r = r0;
    for (; r + 1 < r1; r += 2) {
      float a = (float)hp[(size_t)r * D + c];
      float b = (float)hp[(size_t)(r + 1) * D + c];
      s += a + b;
      m = fmaxf(m, fmaxf(a, b));
    }
    if (r < r1) {
      float a = (float)hp[(size_t)r * D + c];
      s += a;
      m = fmaxf(m, a);
    }
    prow[sub][src * 128 + c] = s;        // k-layout: a1,a2,m1,m2
    prow[sub][256 + src * 128 + c] = m;
  }
  __syncthreads();
  float a00 = 0.f, a01 = 0.f, a10 = 0.f, a11 = 0.f;
  for (int k = 0; k < 512; k += 2) {
    float w0 = W1[(size_t)k * 512 + t];
    float w1 = W1[(size_t)(k + 1) * 512 + t];
    a00 = fmaf(prow[0][k], w0, a00);
    a01 = fmaf(prow[0][k + 1], w1, a01);
    a10 = fmaf(prow[1][k], w0, a10);
    a11 = fmaf(prow[1][k + 1], w1, a11);
  }
  const float bj = b1[t];
  const float w2 = W2[t];
  float acc0 = fmaxf(0.f, a00 + a01 + bj) * w2;
  float acc1 = fmaxf(0.f, a10 + a11 + bj) * w2;
  const int w = t >> 6, l = t & 63;
#pragma unroll
  for (int off = 32; off > 0; off >>= 1) {
    acc0 += __shfl_down(acc0, off);
    acc1 += __shfl_down(acc1, off);
  }
  if (l == 0) {
    shred[w][0] = acc0;
    shred[w][1] = acc1;
  }
  __syncthreads();
  if (t < 2) {
    float s = 0.f;
#pragma unroll
    for (int i = 0; i < 8; i++) s += shred[i][t];
    float h = s + b2[0];
    out[g0 + t] = 1.0f / (1.0f + expf(-h));
    out[GNUM + g0 + t] = h;
  }
}

extern "C" void kernel_launch(void* const* d_in, const int* in_sizes, int n_in,
                              void* d_out, int out_size, void* d_ws,
                              size_t ws_size, hipStream_t stream) {
  const float* x = (const float*)d_in[0];
  const int* ei = (const int*)d_in[1];
  const int* batch = (const int*)d_in[2];
  const float* c1_W1 = (const float*)d_in[3];
  const float* c1_b1 = (const float*)d_in[4];
  const float* c1_g  = (const float*)d_in[5];
  const float* c1_be = (const float*)d_in[6];
  const float* c1_W2 = (const float*)d_in[7];
  const float* c1_b2 = (const float*)d_in[8];
  const float* c2_W1 = (const float*)d_in[9];
  const float* c2_b1 = (const float*)d_in[10];
  const float* c2_g  = (const float*)d_in[11];
  const float* c2_be = (const float*)d_in[12];
  const float* c2_W2 = (const float*)d_in[13];
  const float* c2_b2 = (const float*)d_in[14];
  const float* lin1_W = (const float*)d_in[15];
  const float* lin1_b = (const float*)d_in[16];
  const float* lin2_W = (const float*)d_in[17];
  const float* lin2_b = (const float*)d_in[18];

  const int n = in_sizes[0] / D;        // 50000
  const int nE = in_sizes[1] / 2;       // 600000

  char* p = (char*)d_ws;
  auto take = [&](size_t bytes) {
    char* r = p;
    p += (bytes + 255) & ~(size_t)255;
    return r;
  };
  f16*   hpre   = (f16*)take((size_t)n * D * 2);   // fused GEMM1 out (f16)
  f16*   h2buf  = (f16*)take((size_t)n * D * 2);   // h2
  f16*   h1     = (f16*)take((size_t)n * D * 2);   // x16, then h1
  f16*   wt     = (f16*)take(4 * 16384 * 2);       // 4x W_T f16
  // deg + both stat arenas: contiguous, zeroed by one memset
  int*   deg     = (int*)take((size_t)n * 4);
  float* pstat2a = (float*)take(32 * 256 * 4);
  float* pstat2b = (float*)take(32 * 256 * 4);
  char*  zend    = p;
  float* ssbuf  = (float*)take(256 * 4);
  int*   gstart = (int*)take((GNUM + 1) * 4);
  int* rowptr   = (int*)take((size_t)(n + 1) * 4);
  int* cursor   = (int*)take((size_t)(n + 1) * 4);
  int* partials = (int*)take(128 * 4);
  int* csr      = (int*)take((size_t)nE * 4);
  const int nB = (n + 31) / 32;                    // 1563 gemm blocks

  const int edge_grid = (nE + 255) / 256;
  const int nP = (n + 511) / 512;
  const int n4 = n * D / 4;
  const int nxblk = (n4 + 255) / 256;              // xcvt blocks
  const int prep_grid = nxblk + 259 + edge_grid;   // +wprep +gstart +deg

  // ---------------- prep (deg fused into prep_kernel) ----------------
  hipMemsetAsync(deg, 0, (size_t)(zend - (char*)deg), stream);
  prep_kernel<<<prep_grid, 256, 0, stream>>>(x, h1, n4, c1_W1, c1_W2, c2_W1,
                                             c2_W2, wt, batch, gstart, ei,
                                             deg, nE, n, nxblk);
  partial_kernel<<<nP, 256, 0, stream>>>(deg, partials, n);
  scanp_kernel<<<1, 128, 0, stream>>>(partials, nP, rowptr, n, nE);
  emit_kernel<<<nP, 256, 0, stream>>>(deg, partials, rowptr, cursor, n);
  fill_kernel<<<edge_grid, 256, 0, stream>>>(ei, cursor, csr, nE);

  // ---------------- layer 1 (gather fused into GEMM1) ----------------
  gemmfused_kernel<<<nB, 256, 0, stream>>>(h1, rowptr, csr, wt, c1_b1, hpre,
                                           pstat2a, n);
  bnstats_kernel<<<1, 128, 0, stream>>>(pstat2a, c1_g, c1_be, ssbuf, n);
  gemmbn_kernel<<<nB, 64, 0, stream>>>(hpre, ssbuf, wt + 16384, c1_b2, h1, n);

  // ---------------- layer 2 (gather fused into GEMM1) ----------------
  gemmfused_kernel<<<nB, 256, 0, stream>>>(h1, rowptr, csr, wt + 32768, c2_b1,
                                           hpre, pstat2b, n);
  bnstats_kernel<<<1, 128, 0, stream>>>(pstat2b, c2_g, c2_be, ssbuf, n);
  gemmbn_kernel<<<nB, 64, 0, stream>>>(hpre, ssbuf, wt + 49152, c2_b2,
                                       h2buf, n);

  // ---------------- fused pooling + readout (2 graphs/block) --------------
  poolout_kernel<<<GNUM / 2, 512, 0, stream>>>(h1, h2buf, gstart, lin1_W,
                                               lin1_b, lin2_W, lin2_b,
                                               (float*)d_out);
}